// Round 3
// baseline (1665.696 us; speedup 1.0000x reference)
//
#include <hip/hip_runtime.h>
#include <math.h>

typedef unsigned int uint;
typedef unsigned long long u64;

#define C_ 128
static const int N0 = 65536;
static const int E0 = 1048576;
static const int K0 = 32768, K1 = 16384, K2 = 8192;
static const int CAP1 = 524288, CAP2 = 262144, CAP3 = 131072;

__device__ inline float wave_reduce_sum(float v) {
#pragma unroll
  for (int w = 32; w >= 1; w >>= 1) v += __shfl_xor(v, w, 64);
  return v;
}

// per-row squared norm + score = sqrt(ss + 1e-12). One wave per row.
__global__ void score_kernel(const float* __restrict__ x, float* __restrict__ score,
                             float* __restrict__ ss) {
  int row = blockIdx.x * 4 + (threadIdx.x >> 6);
  int lane = threadIdx.x & 63;
  float2 v = ((const float2*)(x + (size_t)row * C_))[lane];
  float s = v.x * v.x + v.y * v.y;
  s = wave_reduce_sum(s);
  if (lane == 0) { ss[row] = s; score[row] = sqrtf(s + 1e-12f); }
}

// single-block radix select: kth largest key (float bits, all positive) +
// mark boundary-tie elements (lowest indices) with map[i] = -2.
// Ballot-aggregated histogram: scores cluster tightly (||row|| ~ sqrt(128)),
// so naive LDS atomics would serialize ~n-deep on one bucket in high passes.
__global__ __launch_bounds__(1024) void select_kernel(const float* __restrict__ score, int n,
                                                      int k, uint* __restrict__ kth_out,
                                                      int* __restrict__ map) {
  const uint* keys = (const uint*)score;
  const uint4* keys4 = (const uint4*)score;
  __shared__ int hist[256];
  __shared__ uint s_kth;
  __shared__ int s_rem;
  __shared__ int eqlist[2048];
  __shared__ int eqn;
  int tid = threadIdx.x;
  int lane = tid & 63;
  int n4 = n >> 2;
  if (tid == 0) { s_rem = k; s_kth = 0u; eqn = 0; }
  __syncthreads();
  for (int pass = 3; pass >= 0; --pass) {
    int sh = pass * 8;
    if (tid < 256) hist[tid] = 0;
    __syncthreads();
    uint prefix = s_kth;
    uint maskhi = (pass == 3) ? 0u : (0xFFFFFFFFu << (sh + 8));
    for (int i = tid; i < n4; i += 1024) {
      uint4 v4 = keys4[i];
#pragma unroll
      for (int c = 0; c < 4; ++c) {
        uint v = (c == 0) ? v4.x : (c == 1) ? v4.y : (c == 2) ? v4.z : v4.w;
        bool valid = (v & maskhi) == prefix;
        uint b = (v >> sh) & 255u;
        u64 m = __ballot(valid);
#pragma unroll
        for (int bit = 0; bit < 8; ++bit) {
          u64 bb = __ballot((b >> bit) & 1u);
          m &= ((b >> bit) & 1u) ? bb : ~bb;
        }
        if (valid) {
          int leader = __ffsll(m) - 1;
          if (lane == leader) atomicAdd(&hist[b], (int)__popcll(m));
        }
      }
    }
    __syncthreads();
    if (tid == 0) {
      int rem = s_rem;
      int b = 255;
      for (;; --b) { int c = hist[b]; if (c >= rem) break; rem -= c; }
      s_rem = rem;
      s_kth = prefix | ((uint)b << sh);
    }
    __syncthreads();
  }
  uint kth = s_kth;
  for (int i = tid; i < n; i += 1024) {
    if (keys[i] == kth) { int p = atomicAdd(&eqn, 1); if (p < 2048) eqlist[p] = i; }
  }
  __syncthreads();
  if (tid == 0) {
    int need = s_rem;
    int tot = eqn < 2048 ? eqn : 2048;
    for (int t = 0; t < need && t < tot; ++t) {
      int mi = -1, mv = 0x7FFFFFFF;
      for (int q = 0; q < tot; ++q) { int v = eqlist[q]; if (v >= 0 && v < mv) { mv = v; mi = q; } }
      if (mi < 0) break;
      map[mv] = -2;
      eqlist[mi] = -1;
    }
    *kth_out = kth;
  }
}

// compact selected nodes -> perm/map/gate; optionally accumulate the L_FP term
// (L_FP of the PREVIOUS level reuses this level's top-k set: same scores, same k,
// same stable tie-break -> sets identical).
__global__ void build_perm_kernel(const float* __restrict__ score, const float* __restrict__ ss,
                                  const uint* __restrict__ kth_ptr, int* __restrict__ map,
                                  int* __restrict__ perm, float* __restrict__ gate,
                                  int* __restrict__ ctr, float lfp_scale,
                                  float* __restrict__ Lacc) {
  int i = blockIdx.x * 256 + threadIdx.x;
  uint kth = *kth_ptr;
  uint key = ((const uint*)score)[i];
  float lfp = 0.f;
  bool sel = (key > kth) || (map[i] == -2);
  if (sel) {
    int j = atomicAdd(ctr, 1);
    perm[j] = i;
    map[i] = j;
    float t = tanhf(score[i]);
    gate[j] = t;
    if (lfp_scale != 0.f) { float om = 1.f - t; lfp = om * om * ss[i] * lfp_scale; }
  }
  if (lfp_scale != 0.f) {
    lfp = wave_reduce_sum(lfp);
    __shared__ float p[4];
    int lane = threadIdx.x & 63, wid = threadIdx.x >> 6;
    if (lane == 0) p[wid] = lfp;
    __syncthreads();
    if (threadIdx.x == 0) atomicAdd(Lacc, p[0] + p[1] + p[2] + p[3]);
  }
}

// xp[j] = x[perm[j]] * gate[j]   (32 threads/row, float4)
__global__ void pool_gather_kernel(const float* __restrict__ xin, const int* __restrict__ perm,
                                   const float* __restrict__ gate, float* __restrict__ xp) {
  int t = blockIdx.x * 256 + threadIdx.x;
  int j = t >> 5, q = t & 31;
  int p = perm[j];
  float g = gate[j];
  float4 v = ((const float4*)(xin + (size_t)p * C_))[q];
  v.x *= g; v.y *= g; v.z *= g; v.w *= g;
  ((float4*)(xp + (size_t)j * C_))[q] = v;
}

// filter edges whose both endpoints survive; relabel; fused degree histogram.
__global__ void edge_compact_kernel(const int* __restrict__ src, const int* __restrict__ dst,
                                    const int* __restrict__ cnt_ptr, int in_cap,
                                    const int* __restrict__ map, int* __restrict__ osrc,
                                    int* __restrict__ odst, int* __restrict__ octr, int cap,
                                    int* __restrict__ deg) {
  int n = cnt_ptr ? min(*cnt_ptr, in_cap) : in_cap;
  for (int e = blockIdx.x * 256 + threadIdx.x; e < n; e += gridDim.x * 256) {
    int ns = map[src[e]];
    int nd = map[dst[e]];
    if (ns >= 0 && nd >= 0) {
      int p = atomicAdd(octr, 1);
      if (p < cap) {
        osrc[p] = ns;
        odst[p] = nd;
        atomicAdd(&deg[nd], 1);
      }
    }
  }
}

__global__ void hist_kernel(const int* __restrict__ dst, int n, int* __restrict__ deg) {
  for (int e = blockIdx.x * 256 + threadIdx.x; e < n; e += gridDim.x * 256)
    atomicAdd(&deg[dst[e]], 1);
}

// exclusive scan of degrees -> rowptr; cursor doubles as deg-in / offset-out.
__global__ __launch_bounds__(1024) void scan_kernel(int* __restrict__ cursor,
                                                    int* __restrict__ rowptr, int n) {
  __shared__ int part[1024];
  int tid = threadIdx.x;
  int chunk = (n + 1023) >> 10;
  int beg = tid * chunk, end = min(beg + chunk, n);
  int s = 0;
  for (int i = beg; i < end; ++i) s += cursor[i];
  part[tid] = s;
  __syncthreads();
  for (int d = 1; d < 1024; d <<= 1) {
    int v = part[tid];
    if (tid >= d) v += part[tid - d];
    __syncthreads();
    part[tid] = v;
    __syncthreads();
  }
  int off = part[tid] - s;
  for (int i = beg; i < end; ++i) { int dv = cursor[i]; rowptr[i] = off; cursor[i] = off; off += dv; }
  if (tid == 1023) rowptr[n] = part[1023];
}

__global__ void scatter_kernel(const int* __restrict__ src, const int* __restrict__ dst,
                               const int* __restrict__ cnt_ptr, int cap,
                               int* __restrict__ cursor, int* __restrict__ csr) {
  int n = cnt_ptr ? min(*cnt_ptr, cap) : cap;
  for (int e = blockIdx.x * 256 + threadIdx.x; e < n; e += gridDim.x * 256) {
    int p = atomicAdd(&cursor[dst[e]], 1);
    csr[p] = src[e];
  }
}

// mean[node] = (sum over CSR row) / max(deg,1). 32 threads/node, float4.
// fmap mode: source ids are in the PREVIOUS space; x row = x[fmap[s]] if
// selected, else contributes 0 (virtual unpool -- never materialized).
__global__ void agg_kernel(const float* __restrict__ x, const int* __restrict__ rowptr,
                           const int* __restrict__ csr, const int* __restrict__ fmap,
                           float* __restrict__ mean, int n) {
  int t = blockIdx.x * 256 + threadIdx.x;
  int node = t >> 5, q = t & 31;
  if (node >= n) return;
  int beg = rowptr[node], end = rowptr[node + 1];
  float4 acc = make_float4(0.f, 0.f, 0.f, 0.f);
  if (fmap) {
    for (int p = beg; p < end; ++p) {
      int m = fmap[csr[p]];
      if (m < 0) continue;
      float4 v = ((const float4*)(x + (size_t)m * C_))[q];
      acc.x += v.x; acc.y += v.y; acc.z += v.z; acc.w += v.w;
    }
  } else {
    for (int p = beg; p < end; ++p) {
      int s = csr[p];
      float4 v = ((const float4*)(x + (size_t)s * C_))[q];
      acc.x += v.x; acc.y += v.y; acc.z += v.z; acc.w += v.w;
    }
  }
  float inv = 1.f / fmaxf((float)(end - beg), 1.f);
  acc.x *= inv; acc.y *= inv; acc.z *= inv; acc.w *= inv;
  ((float4*)(mean + (size_t)node * C_))[q] = acc;
}

// out[row] = mean[row] @ Wl + Xsrc[xrow] @ Wr + b (optional relu).
// xmask==nullptr: Xsrc dense, xrow = row. xmask!=nullptr: xrow = xmask[row],
// rows with xmask<0 are zero (virtual unpool). Lout: fused loss writeback.
__global__ __launch_bounds__(256) void gemm_kernel(const float* __restrict__ Amean,
                                                   const float* __restrict__ Xsrc,
                                                   const int* __restrict__ xmask,
                                                   const float* __restrict__ Wl,
                                                   const float* __restrict__ Wr,
                                                   const float* __restrict__ bias,
                                                   float* __restrict__ out, int relu,
                                                   float* __restrict__ Lout,
                                                   const float* __restrict__ Lacc) {
  __shared__ alignas(16) float As[32][68];
  __shared__ alignas(16) float Ws[32][128];
  __shared__ int rm[64];
  int tid = threadIdx.x;
  int row0 = blockIdx.x * 64;
  if (tid < 64) rm[tid] = xmask ? xmask[row0 + tid] : (row0 + tid);
  if (Lout && blockIdx.x == 0 && tid == 0) Lout[0] = *Lacc;
  int trow = tid >> 4;  // 0..15 -> 4 rows each
  int tcol = tid & 15;  // 0..15 -> 8 cols each
  float acc[4][8];
#pragma unroll
  for (int i = 0; i < 4; ++i)
#pragma unroll
    for (int j = 0; j < 8; ++j) acc[i][j] = 0.f;
  __syncthreads();  // rm visible before phase-1 staging (first use is later anyway)
  for (int phase = 0; phase < 2; ++phase) {
    const float* A = phase ? Xsrc : Amean;
    const float* W = phase ? Wr : Wl;
    for (int kc = 0; kc < 128; kc += 32) {
      // stage A chunk: 64 rows x 32 k, float4 granularity (512 float4, 2/thread)
#pragma unroll
      for (int l = 0; l < 2; ++l) {
        int f = tid + l * 256;
        int r = f >> 3, c4 = (f & 7) << 2;
        int xr = phase ? rm[r] : (row0 + r);
        float4 v = make_float4(0.f, 0.f, 0.f, 0.f);
        if (xr >= 0) v = *(const float4*)(A + (size_t)xr * C_ + kc + c4);
        As[c4 + 0][r] = v.x; As[c4 + 1][r] = v.y; As[c4 + 2][r] = v.z; As[c4 + 3][r] = v.w;
      }
      // stage W chunk: 32 k x 128 cols (1024 float4, 4/thread)
#pragma unroll
      for (int l = 0; l < 4; ++l) {
        int f = tid + l * 256;
        int kk = f >> 5, c4 = (f & 31) << 2;
        *(float4*)(&Ws[kk][c4]) = *(const float4*)(W + (size_t)(kc + kk) * C_ + c4);
      }
      __syncthreads();
#pragma unroll
      for (int kk = 0; kk < 32; ++kk) {
        float a[4], w[8];
#pragma unroll
        for (int i = 0; i < 4; ++i) a[i] = As[kk][trow * 4 + i];
#pragma unroll
        for (int j = 0; j < 8; ++j) w[j] = Ws[kk][tcol * 8 + j];
#pragma unroll
        for (int i = 0; i < 4; ++i)
#pragma unroll
          for (int j = 0; j < 8; ++j) acc[i][j] = fmaf(a[i], w[j], acc[i][j]);
      }
      __syncthreads();
    }
  }
#pragma unroll
  for (int i = 0; i < 4; ++i) {
    int r = row0 + trow * 4 + i;
#pragma unroll
    for (int j = 0; j < 8; ++j) {
      float v = acc[i][j] + bias[tcol * 8 + j];
      if (relu) v = fmaxf(v, 0.f);
      out[(size_t)r * C_ + tcol * 8 + j] = v;
    }
  }
}

// fused: L_similarity + L_regularization for one level, plus next level's
// score/ss (row norms of h). One wave per row.
__global__ void lsim_score_kernel(const float* __restrict__ h, const float* __restrict__ x0,
                                  const float* __restrict__ xin, const int* __restrict__ perm,
                                  float scale, float* __restrict__ Lacc,
                                  float* __restrict__ score, float* __restrict__ ss) {
  int row = blockIdx.x * 4 + (threadIdx.x >> 6);
  int lane = threadIdx.x & 63;
  int p = perm[row];
  float2 hv = ((const float2*)(h + (size_t)row * C_))[lane];
  float2 a = ((const float2*)(x0 + (size_t)p * C_))[lane];
  float2 bv = (xin == x0) ? a : ((const float2*)(xin + (size_t)p * C_))[lane];
  float d1x = hv.x - a.x, d1y = hv.y - a.y;
  float l = d1x * d1x + d1y * d1y + fabsf(hv.x - bv.x) + fabsf(hv.y - bv.y);
  float s2 = hv.x * hv.x + hv.y * hv.y;
#pragma unroll
  for (int w = 32; w >= 1; w >>= 1) { l += __shfl_xor(l, w, 64); s2 += __shfl_xor(s2, w, 64); }
  __shared__ float pl[4];
  int wid = threadIdx.x >> 6;
  if (lane == 0) {
    pl[wid] = l;
    if (score) { ss[row] = s2; score[row] = sqrtf(s2 + 1e-12f); }
  }
  __syncthreads();
  if (threadIdx.x == 0) atomicAdd(Lacc, (pl[0] + pl[1] + pl[2] + pl[3]) * scale);
}

extern "C" void kernel_launch(void* const* d_in, const int* in_sizes, int n_in, void* d_out,
                              int out_size, void* d_ws, size_t ws_size, hipStream_t stream) {
  const float* x0 = (const float*)d_in[0];
  const int* ei = (const int*)d_in[1];
  const float* Wl = (const float*)d_in[2];
  const float* Wr = (const float*)d_in[3];
  const float* bias = (const float*)d_in[4];
  float* out = (float*)d_out;

  char* base = (char*)d_ws;
  size_t off = 0;
  auto alloc = [&](size_t bytes) -> char* {
    char* p = base + off;
    off = (off + bytes + 255) & ~(size_t)255;
    return p;
  };

  // ---- zeroed region (one memset) ----
  int* ctrl = (int*)alloc(1024 * 4);
  // ctrl ints: 0..2 edge counters, 4..6 perm counters, 8..10 kth keys, 16 Lacc(float)
  int* cur0 = (int*)alloc((size_t)(N0 + 1) * 4);
  int* cur1 = (int*)alloc((size_t)(K0 + 1) * 4);
  int* cur2 = (int*)alloc((size_t)(K1 + 1) * 4);
  int* cur3 = (int*)alloc((size_t)(K2 + 1) * 4);
  size_t zero_bytes = (size_t)((base + off) - (char*)ctrl);
  // ---- 0xFF region (one memset) ----
  int* map0 = (int*)alloc((size_t)N0 * 4);
  int* map1 = (int*)alloc((size_t)K0 * 4);
  int* map2 = (int*)alloc((size_t)K1 * 4);
  size_t ff_bytes = (size_t)((base + off) - (char*)map0);
  // ---- uninitialized (fully written before read every call) ----
  float* score0 = (float*)alloc((size_t)N0 * 4);
  float* ss0 = (float*)alloc((size_t)N0 * 4);
  float* score1 = (float*)alloc((size_t)K0 * 4);
  float* ss1 = (float*)alloc((size_t)K0 * 4);
  float* score2 = (float*)alloc((size_t)K1 * 4);
  float* ss2 = (float*)alloc((size_t)K1 * 4);
  int* perm0 = (int*)alloc((size_t)K0 * 4);
  int* perm1 = (int*)alloc((size_t)K1 * 4);
  int* perm2 = (int*)alloc((size_t)K2 * 4);
  float* gate0 = (float*)alloc((size_t)K0 * 4);
  float* gate1 = (float*)alloc((size_t)K1 * 4);
  float* gate2 = (float*)alloc((size_t)K2 * 4);
  int* e1s = (int*)alloc((size_t)CAP1 * 4);
  int* e1d = (int*)alloc((size_t)CAP1 * 4);
  int* e2s = (int*)alloc((size_t)CAP2 * 4);
  int* e2d = (int*)alloc((size_t)CAP2 * 4);
  int* e3s = (int*)alloc((size_t)CAP3 * 4);
  int* e3d = (int*)alloc((size_t)CAP3 * 4);
  int* rowptr0 = (int*)alloc((size_t)(N0 + 1) * 4);
  int* rowptr1 = (int*)alloc((size_t)(K0 + 1) * 4);
  int* rowptr2 = (int*)alloc((size_t)(K1 + 1) * 4);
  int* rowptr3 = (int*)alloc((size_t)(K2 + 1) * 4);
  int* csr0 = (int*)alloc((size_t)E0 * 4);
  int* csr1 = (int*)alloc((size_t)CAP1 * 4);
  int* csr2 = (int*)alloc((size_t)CAP2 * 4);
  int* csr3 = (int*)alloc((size_t)CAP3 * 4);
  float* xp = (float*)alloc((size_t)K0 * C_ * 4);  // pooled input / hup2
  float* h0 = (float*)alloc((size_t)K0 * C_ * 4);  // down h0, later hup1
  float* h1 = (float*)alloc((size_t)K1 * C_ * 4);
  float* h2 = (float*)alloc((size_t)K2 * C_ * 4);
  float* mean = (float*)alloc((size_t)N0 * C_ * 4);

  uint* kth0 = (uint*)(ctrl + 8);
  uint* kth1 = (uint*)(ctrl + 9);
  uint* kth2 = (uint*)(ctrl + 10);
  float* Lacc = (float*)(ctrl + 16);
  const float sc0 = 1.f / ((float)K0 * C_);
  const float sc1 = 1.f / ((float)K1 * C_);
  const float sc2 = 1.f / ((float)K2 * C_);

  hipMemsetAsync(ctrl, 0, zero_bytes, stream);
  hipMemsetAsync(map0, 0xFF, ff_bytes, stream);

  // CSR over original edges (for the final conv)
  hist_kernel<<<2048, 256, 0, stream>>>(ei + E0, E0, cur0);
  scan_kernel<<<1, 1024, 0, stream>>>(cur0, rowptr0, N0);
  scatter_kernel<<<2048, 256, 0, stream>>>(ei, ei + E0, nullptr, E0, cur0, csr0);

  // ---------------- down level 0 ----------------
  score_kernel<<<N0 / 4, 256, 0, stream>>>(x0, score0, ss0);
  select_kernel<<<1, 1024, 0, stream>>>(score0, N0, K0, kth0, map0);
  build_perm_kernel<<<N0 / 256, 256, 0, stream>>>(score0, ss0, kth0, map0, perm0, gate0,
                                                  ctrl + 4, 0.f, Lacc);
  pool_gather_kernel<<<K0 / 8, 256, 0, stream>>>(x0, perm0, gate0, xp);
  edge_compact_kernel<<<2048, 256, 0, stream>>>(ei, ei + E0, nullptr, E0, map0, e1s, e1d,
                                                ctrl + 0, CAP1, cur1);
  scan_kernel<<<1, 1024, 0, stream>>>(cur1, rowptr1, K0);
  scatter_kernel<<<1024, 256, 0, stream>>>(e1s, e1d, ctrl + 0, CAP1, cur1, csr1);
  agg_kernel<<<K0 / 8, 256, 0, stream>>>(xp, rowptr1, csr1, nullptr, mean, K0);
  gemm_kernel<<<K0 / 64, 256, 0, stream>>>(mean, xp, nullptr, Wl, Wr, bias, h0, 1, nullptr, Lacc);
  lsim_score_kernel<<<K0 / 4, 256, 0, stream>>>(h0, x0, x0, perm0, sc0, Lacc, score1, ss1);

  // ---------------- down level 1 ----------------
  select_kernel<<<1, 1024, 0, stream>>>(score1, K0, K1, kth1, map1);
  build_perm_kernel<<<K0 / 256, 256, 0, stream>>>(score1, ss1, kth1, map1, perm1, gate1,
                                                  ctrl + 5, sc1, Lacc);  // + fused L_FP0
  pool_gather_kernel<<<K1 / 8, 256, 0, stream>>>(h0, perm1, gate1, xp);
  edge_compact_kernel<<<1024, 256, 0, stream>>>(e1s, e1d, ctrl + 0, CAP1, map1, e2s, e2d,
                                                ctrl + 1, CAP2, cur2);
  scan_kernel<<<1, 1024, 0, stream>>>(cur2, rowptr2, K1);
  scatter_kernel<<<512, 256, 0, stream>>>(e2s, e2d, ctrl + 1, CAP2, cur2, csr2);
  agg_kernel<<<K1 / 8, 256, 0, stream>>>(xp, rowptr2, csr2, nullptr, mean, K1);
  gemm_kernel<<<K1 / 64, 256, 0, stream>>>(mean, xp, nullptr, Wl + 16384, Wr + 16384, bias + 128,
                                           h1, 1, nullptr, Lacc);
  lsim_score_kernel<<<K1 / 4, 256, 0, stream>>>(h1, x0, h0, perm1, sc1, Lacc, score2, ss2);

  // ---------------- down level 2 ----------------
  select_kernel<<<1, 1024, 0, stream>>>(score2, K1, K2, kth2, map2);
  build_perm_kernel<<<K1 / 256, 256, 0, stream>>>(score2, ss2, kth2, map2, perm2, gate2,
                                                  ctrl + 6, sc2, Lacc);  // + fused L_FP1
  pool_gather_kernel<<<K2 / 8, 256, 0, stream>>>(h1, perm2, gate2, xp);
  edge_compact_kernel<<<512, 256, 0, stream>>>(e2s, e2d, ctrl + 1, CAP2, map2, e3s, e3d,
                                               ctrl + 2, CAP3, cur3);
  scan_kernel<<<1, 1024, 0, stream>>>(cur3, rowptr3, K2);
  scatter_kernel<<<256, 256, 0, stream>>>(e3s, e3d, ctrl + 2, CAP3, cur3, csr3);
  agg_kernel<<<K2 / 8, 256, 0, stream>>>(xp, rowptr3, csr3, nullptr, mean, K2);
  gemm_kernel<<<K2 / 64, 256, 0, stream>>>(mean, xp, nullptr, Wl + 2 * 16384, Wr + 2 * 16384,
                                           bias + 256, h2, 1, nullptr, Lacc);
  lsim_score_kernel<<<K2 / 4, 256, 0, stream>>>(h2, x0, h1, perm2, sc2, Lacc, nullptr, nullptr);

  // ---------------- up path: unpool is VIRTUAL (indirection via map) ----------
  // i = 2: conv idx 4 over level-2 graph (K1 nodes); x = h2 via map2; -> xp
  agg_kernel<<<K1 / 8, 256, 0, stream>>>(h2, rowptr2, csr2, map2, mean, K1);
  gemm_kernel<<<K1 / 64, 256, 0, stream>>>(mean, h2, map2, Wl + 4 * 16384, Wr + 4 * 16384,
                                           bias + 512, xp, 1, nullptr, Lacc);
  // i = 1: conv idx 3 over level-1 graph (K0 nodes); x = xp via map1; -> h0
  agg_kernel<<<K0 / 8, 256, 0, stream>>>(xp, rowptr1, csr1, map1, mean, K0);
  gemm_kernel<<<K0 / 64, 256, 0, stream>>>(mean, xp, map1, Wl + 3 * 16384, Wr + 3 * 16384,
                                           bias + 384, h0, 1, nullptr, Lacc);
  // final: conv idx 5 over original graph; x = h0 via map0; no relu; + L writeback
  agg_kernel<<<N0 / 8, 256, 0, stream>>>(h0, rowptr0, csr0, map0, mean, N0);
  gemm_kernel<<<N0 / 64, 256, 0, stream>>>(mean, h0, map0, Wl + 5 * 16384, Wr + 5 * 16384,
                                           bias + 640, out, 0, out + (size_t)N0 * C_, Lacc);
}

// Round 6
// 1618.103 us; speedup vs baseline: 1.0294x; 1.0294x over previous
//
#include <hip/hip_runtime.h>
#include <math.h>

typedef unsigned int uint;
typedef unsigned long long u64;

#define C_ 128
static const int N0 = 65536;
static const int E0 = 1048576;
static const int K0 = 32768, K1 = 16384, K2 = 8192;
static const int CAP1 = 524288, CAP2 = 262144, CAP3 = 131072;

__device__ inline float wave_reduce_sum(float v) {
#pragma unroll
  for (int w = 32; w >= 1; w >>= 1) v += __shfl_xor(v, w, 64);
  return v;
}

// wave-aggregated compaction slot: one atomic per wave instead of per lane.
// Returns this lane's slot (valid only if keep), or -1.
__device__ inline int wave_compact_slot(bool keep, int* ctr) {
  u64 m = __ballot(keep);
  if (!m) return -1;
  int lane = threadIdx.x & 63;
  int leader = __ffsll((unsigned long long)m) - 1;
  int base = 0;
  if (lane == leader) base = atomicAdd(ctr, (int)__popcll(m));
  base = __shfl(base, leader, 64);
  return keep ? base + (int)__popcll(m & ((1ull << lane) - 1ull)) : -1;
}

// per-row squared norm + score = sqrt(ss + 1e-12). One wave per row.
__global__ void score_kernel(const float* __restrict__ x, float* __restrict__ score,
                             float* __restrict__ ss) {
  int row = blockIdx.x * 4 + (threadIdx.x >> 6);
  int lane = threadIdx.x & 63;
  float2 v = ((const float2*)(x + (size_t)row * C_))[lane];
  float s = v.x * v.x + v.y * v.y;
  s = wave_reduce_sum(s);
  if (lane == 0) { ss[row] = s; score[row] = sqrtf(s + 1e-12f); }
}

// single-block radix select: kth largest key (float bits, all positive) +
// mark boundary-tie elements (lowest indices) with map[i] = -2.
// Ballot-aggregated histogram: scores cluster tightly (||row|| ~ sqrt(128)),
// so naive LDS atomics would serialize ~n-deep on one bucket in high passes.
// Passes <3: wave-uniform skip when no lane matches the prefix (~255/256 of
// iterations) -- saves the 8-ballot bucket-mask sequence.
__global__ __launch_bounds__(1024) void select_kernel(const float* __restrict__ score, int n,
                                                      int k, uint* __restrict__ kth_out,
                                                      int* __restrict__ map) {
  const uint* keys = (const uint*)score;
  const uint4* keys4 = (const uint4*)score;
  __shared__ int hist[256];
  __shared__ uint s_kth;
  __shared__ int s_rem;
  __shared__ int eqlist[2048];
  __shared__ int eqn;
  int tid = threadIdx.x;
  int lane = tid & 63;
  int n4 = n >> 2;
  if (tid == 0) { s_rem = k; s_kth = 0u; eqn = 0; }
  __syncthreads();
  for (int pass = 3; pass >= 0; --pass) {
    int sh = pass * 8;
    if (tid < 256) hist[tid] = 0;
    __syncthreads();
    uint prefix = s_kth;
    uint maskhi = (pass == 3) ? 0u : (0xFFFFFFFFu << (sh + 8));
    for (int i = tid; i < n4; i += 1024) {
      uint4 v4 = keys4[i];
#pragma unroll
      for (int c = 0; c < 4; ++c) {
        uint v = (c == 0) ? v4.x : (c == 1) ? v4.y : (c == 2) ? v4.z : v4.w;
        bool valid = (v & maskhi) == prefix;
        u64 m = __ballot(valid);
        if (!m) continue;  // wave-uniform: nobody matches prefix
        uint b = (v >> sh) & 255u;
#pragma unroll
        for (int bit = 0; bit < 8; ++bit) {
          u64 bb = __ballot((b >> bit) & 1u);
          m &= ((b >> bit) & 1u) ? bb : ~bb;
        }
        if (valid) {
          int leader = __ffsll(m) - 1;
          if (lane == leader) atomicAdd(&hist[b], (int)__popcll(m));
        }
      }
    }
    __syncthreads();
    if (tid == 0) {
      int rem = s_rem;
      int b = 255;
      for (;; --b) { int c = hist[b]; if (c >= rem) break; rem -= c; }
      s_rem = rem;
      s_kth = prefix | ((uint)b << sh);
    }
    __syncthreads();
  }
  uint kth = s_kth;
  for (int i = tid; i < n; i += 1024) {
    if (keys[i] == kth) { int p = atomicAdd(&eqn, 1); if (p < 2048) eqlist[p] = i; }
  }
  __syncthreads();
  if (tid == 0) {
    int need = s_rem;
    int tot = eqn < 2048 ? eqn : 2048;
    for (int t = 0; t < need && t < tot; ++t) {
      int mi = -1, mv = 0x7FFFFFFF;
      for (int q = 0; q < tot; ++q) { int v = eqlist[q]; if (v >= 0 && v < mv) { mv = v; mi = q; } }
      if (mi < 0) break;
      map[mv] = -2;
      eqlist[mi] = -1;
    }
    *kth_out = kth;
  }
}

// compact selected nodes -> perm/map/gate; optionally accumulate the L_FP term
// (L_FP of the PREVIOUS level reuses this level's top-k set: same scores, same k,
// same stable tie-break -> sets identical). Wave-aggregated counter.
__global__ void build_perm_kernel(const float* __restrict__ score, const float* __restrict__ ss,
                                  const uint* __restrict__ kth_ptr, int* __restrict__ map,
                                  int* __restrict__ perm, float* __restrict__ gate,
                                  int* __restrict__ ctr, float lfp_scale,
                                  float* __restrict__ Lacc) {
  int i = blockIdx.x * 256 + threadIdx.x;
  uint kth = *kth_ptr;
  uint key = ((const uint*)score)[i];
  float lfp = 0.f;
  bool sel = (key > kth) || (map[i] == -2);
  int j = wave_compact_slot(sel, ctr);
  if (sel) {
    perm[j] = i;
    map[i] = j;
    float t = tanhf(score[i]);
    gate[j] = t;
    if (lfp_scale != 0.f) { float om = 1.f - t; lfp = om * om * ss[i] * lfp_scale; }
  }
  if (lfp_scale != 0.f) {
    lfp = wave_reduce_sum(lfp);
    __shared__ float p[4];
    int lane = threadIdx.x & 63, wid = threadIdx.x >> 6;
    if (lane == 0) p[wid] = lfp;
    __syncthreads();
    if (threadIdx.x == 0) atomicAdd(Lacc, p[0] + p[1] + p[2] + p[3]);
  }
}

// xp[j] = x[perm[j]] * gate[j]   (32 threads/row, float4)
__global__ void pool_gather_kernel(const float* __restrict__ xin, const int* __restrict__ perm,
                                   const float* __restrict__ gate, float* __restrict__ xp) {
  int t = blockIdx.x * 256 + threadIdx.x;
  int j = t >> 5, q = t & 31;
  int p = perm[j];
  float g = gate[j];
  float4 v = ((const float4*)(xin + (size_t)p * C_))[q];
  v.x *= g; v.y *= g; v.z *= g; v.w *= g;
  ((float4*)(xp + (size_t)j * C_))[q] = v;
}

// filter edges whose both endpoints survive; relabel; fused degree histogram.
// Wave-aggregated output-slot allocation (was: one same-address atomic PER EDGE
// -- measured 193us at VALUBusy 0.35%, pure atomic serialization).
__global__ void edge_compact_kernel(const int* __restrict__ src, const int* __restrict__ dst,
                                    const int* __restrict__ cnt_ptr, int in_cap,
                                    const int* __restrict__ map, int* __restrict__ osrc,
                                    int* __restrict__ odst, int* __restrict__ octr, int cap,
                                    int* __restrict__ deg) {
  int n = cnt_ptr ? min(*cnt_ptr, in_cap) : in_cap;
  for (int e = blockIdx.x * 256 + threadIdx.x; e < n; e += gridDim.x * 256) {
    int ns = map[src[e]];
    int nd = map[dst[e]];
    bool keep = (ns >= 0 && nd >= 0);
    int p = wave_compact_slot(keep, octr);
    if (keep && p < cap) {
      osrc[p] = ns;
      odst[p] = nd;
      atomicAdd(&deg[nd], 1);
    }
  }
}

__global__ void hist_kernel(const int* __restrict__ dst, int n, int* __restrict__ deg) {
  for (int e = blockIdx.x * 256 + threadIdx.x; e < n; e += gridDim.x * 256)
    atomicAdd(&deg[dst[e]], 1);
}

// exclusive scan of degrees -> rowptr; cursor doubles as deg-in / offset-out.
__global__ __launch_bounds__(1024) void scan_kernel(int* __restrict__ cursor,
                                                    int* __restrict__ rowptr, int n) {
  __shared__ int part[1024];
  int tid = threadIdx.x;
  int chunk = (n + 1023) >> 10;
  int beg = tid * chunk, end = min(beg + chunk, n);
  int s = 0;
  for (int i = beg; i < end; ++i) s += cursor[i];
  part[tid] = s;
  __syncthreads();
  for (int d = 1; d < 1024; d <<= 1) {
    int v = part[tid];
    if (tid >= d) v += part[tid - d];
    __syncthreads();
    part[tid] = v;
    __syncthreads();
  }
  int off = part[tid] - s;
  for (int i = beg; i < end; ++i) { int dv = cursor[i]; rowptr[i] = off; cursor[i] = off; off += dv; }
  if (tid == 1023) rowptr[n] = part[1023];
}

__global__ void scatter_kernel(const int* __restrict__ src, const int* __restrict__ dst,
                               const int* __restrict__ cnt_ptr, int cap,
                               int* __restrict__ cursor, int* __restrict__ csr) {
  int n = cnt_ptr ? min(*cnt_ptr, cap) : cap;
  for (int e = blockIdx.x * 256 + threadIdx.x; e < n; e += gridDim.x * 256) {
    int p = atomicAdd(&cursor[dst[e]], 1);
    csr[p] = src[e];
  }
}

// mean[node] = (sum over CSR row) / max(deg,1). 32 threads/node, float4.
// fmap mode: source ids are in the PREVIOUS space; x row = x[fmap[s]] if
// selected, else contributes 0 (virtual unpool -- never materialized).
__global__ void agg_kernel(const float* __restrict__ x, const int* __restrict__ rowptr,
                           const int* __restrict__ csr, const int* __restrict__ fmap,
                           float* __restrict__ mean, int n) {
  int t = blockIdx.x * 256 + threadIdx.x;
  int node = t >> 5, q = t & 31;
  if (node >= n) return;
  int beg = rowptr[node], end = rowptr[node + 1];
  float4 acc = make_float4(0.f, 0.f, 0.f, 0.f);
  if (fmap) {
    for (int p = beg; p < end; ++p) {
      int m = fmap[csr[p]];
      if (m < 0) continue;
      float4 v = ((const float4*)(x + (size_t)m * C_))[q];
      acc.x += v.x; acc.y += v.y; acc.z += v.z; acc.w += v.w;
    }
  } else {
    for (int p = beg; p < end; ++p) {
      int s = csr[p];
      float4 v = ((const float4*)(x + (size_t)s * C_))[q];
      acc.x += v.x; acc.y += v.y; acc.z += v.z; acc.w += v.w;
    }
  }
  float inv = 1.f / fmaxf((float)(end - beg), 1.f);
  acc.x *= inv; acc.y *= inv; acc.z *= inv; acc.w *= inv;
  ((float4*)(mean + (size_t)node * C_))[q] = acc;
}

// out[row] = mean[row] @ Wl + Xsrc[xrow] @ Wr + b (optional relu).
// xmask==nullptr: Xsrc dense, xrow = row. xmask!=nullptr: xrow = xmask[row],
// rows with xmask<0 are zero (virtual unpool). Lout: fused loss writeback.
__global__ __launch_bounds__(256) void gemm_kernel(const float* __restrict__ Amean,
                                                   const float* __restrict__ Xsrc,
                                                   const int* __restrict__ xmask,
                                                   const float* __restrict__ Wl,
                                                   const float* __restrict__ Wr,
                                                   const float* __restrict__ bias,
                                                   float* __restrict__ out, int relu,
                                                   float* __restrict__ Lout,
                                                   const float* __restrict__ Lacc) {
  __shared__ alignas(16) float As[32][68];
  __shared__ alignas(16) float Ws[32][128];
  __shared__ int rm[64];
  int tid = threadIdx.x;
  int row0 = blockIdx.x * 64;
  if (tid < 64) rm[tid] = xmask ? xmask[row0 + tid] : (row0 + tid);
  if (Lout && blockIdx.x == 0 && tid == 0) Lout[0] = *Lacc;
  int trow = tid >> 4;  // 0..15 -> 4 rows each
  int tcol = tid & 15;  // 0..15 -> 8 cols each
  float acc[4][8];
#pragma unroll
  for (int i = 0; i < 4; ++i)
#pragma unroll
    for (int j = 0; j < 8; ++j) acc[i][j] = 0.f;
  __syncthreads();  // rm visible before phase-1 staging
  for (int phase = 0; phase < 2; ++phase) {
    const float* A = phase ? Xsrc : Amean;
    const float* W = phase ? Wr : Wl;
    for (int kc = 0; kc < 128; kc += 32) {
      // stage A chunk: 64 rows x 32 k, float4 granularity (512 float4, 2/thread)
#pragma unroll
      for (int l = 0; l < 2; ++l) {
        int f = tid + l * 256;
        int r = f >> 3, c4 = (f & 7) << 2;
        int xr = phase ? rm[r] : (row0 + r);
        float4 v = make_float4(0.f, 0.f, 0.f, 0.f);
        if (xr >= 0) v = *(const float4*)(A + (size_t)xr * C_ + kc + c4);
        As[c4 + 0][r] = v.x; As[c4 + 1][r] = v.y; As[c4 + 2][r] = v.z; As[c4 + 3][r] = v.w;
      }
      // stage W chunk: 32 k x 128 cols (1024 float4, 4/thread)
#pragma unroll
      for (int l = 0; l < 4; ++l) {
        int f = tid + l * 256;
        int kk = f >> 5, c4 = (f & 31) << 2;
        *(float4*)(&Ws[kk][c4]) = *(const float4*)(W + (size_t)(kc + kk) * C_ + c4);
      }
      __syncthreads();
#pragma unroll
      for (int kk = 0; kk < 32; ++kk) {
        float a[4], w[8];
#pragma unroll
        for (int i = 0; i < 4; ++i) a[i] = As[kk][trow * 4 + i];
#pragma unroll
        for (int j = 0; j < 8; ++j) w[j] = Ws[kk][tcol * 8 + j];
#pragma unroll
        for (int i = 0; i < 4; ++i)
#pragma unroll
          for (int j = 0; j < 8; ++j) acc[i][j] = fmaf(a[i], w[j], acc[i][j]);
      }
      __syncthreads();
    }
  }
#pragma unroll
  for (int i = 0; i < 4; ++i) {
    int r = row0 + trow * 4 + i;
#pragma unroll
    for (int j = 0; j < 8; ++j) {
      float v = acc[i][j] + bias[tcol * 8 + j];
      if (relu) v = fmaxf(v, 0.f);
      out[(size_t)r * C_ + tcol * 8 + j] = v;
    }
  }
}

// fused: L_similarity + L_regularization for one level, plus next level's
// score/ss (row norms of h). One wave per row.
__global__ void lsim_score_kernel(const float* __restrict__ h, const float* __restrict__ x0,
                                  const float* __restrict__ xin, const int* __restrict__ perm,
                                  float scale, float* __restrict__ Lacc,
                                  float* __restrict__ score, float* __restrict__ ss) {
  int row = blockIdx.x * 4 + (threadIdx.x >> 6);
  int lane = threadIdx.x & 63;
  int p = perm[row];
  float2 hv = ((const float2*)(h + (size_t)row * C_))[lane];
  float2 a = ((const float2*)(x0 + (size_t)p * C_))[lane];
  float2 bv = (xin == x0) ? a : ((const float2*)(xin + (size_t)p * C_))[lane];
  float d1x = hv.x - a.x, d1y = hv.y - a.y;
  float l = d1x * d1x + d1y * d1y + fabsf(hv.x - bv.x) + fabsf(hv.y - bv.y);
  float s2 = hv.x * hv.x + hv.y * hv.y;
#pragma unroll
  for (int w = 32; w >= 1; w >>= 1) { l += __shfl_xor(l, w, 64); s2 += __shfl_xor(s2, w, 64); }
  __shared__ float pl[4];
  int wid = threadIdx.x >> 6;
  if (lane == 0) {
    pl[wid] = l;
    if (score) { ss[row] = s2; score[row] = sqrtf(s2 + 1e-12f); }
  }
  __syncthreads();
  if (threadIdx.x == 0) atomicAdd(Lacc, (pl[0] + pl[1] + pl[2] + pl[3]) * scale);
}

extern "C" void kernel_launch(void* const* d_in, const int* in_sizes, int n_in, void* d_out,
                              int out_size, void* d_ws, size_t ws_size, hipStream_t stream) {
  const float* x0 = (const float*)d_in[0];
  const int* ei = (const int*)d_in[1];
  const float* Wl = (const float*)d_in[2];
  const float* Wr = (const float*)d_in[3];
  const float* bias = (const float*)d_in[4];
  float* out = (float*)d_out;

  char* base = (char*)d_ws;
  size_t off = 0;
  auto alloc = [&](size_t bytes) -> char* {
    char* p = base + off;
    off = (off + bytes + 255) & ~(size_t)255;
    return p;
  };

  // ---- zeroed region (one memset) ----
  int* ctrl = (int*)alloc(1024 * 4);
  // ctrl ints: 0..2 edge counters, 4..6 perm counters, 8..10 kth keys, 16 Lacc(float)
  int* cur0 = (int*)alloc((size_t)(N0 + 1) * 4);
  int* cur1 = (int*)alloc((size_t)(K0 + 1) * 4);
  int* cur2 = (int*)alloc((size_t)(K1 + 1) * 4);
  int* cur3 = (int*)alloc((size_t)(K2 + 1) * 4);
  size_t zero_bytes = (size_t)((base + off) - (char*)ctrl);
  // ---- 0xFF region (one memset) ----
  int* map0 = (int*)alloc((size_t)N0 * 4);
  int* map1 = (int*)alloc((size_t)K0 * 4);
  int* map2 = (int*)alloc((size_t)K1 * 4);
  size_t ff_bytes = (size_t)((base + off) - (char*)map0);
  // ---- uninitialized (fully written before read every call) ----
  float* score0 = (float*)alloc((size_t)N0 * 4);
  float* ss0 = (float*)alloc((size_t)N0 * 4);
  float* score1 = (float*)alloc((size_t)K0 * 4);
  float* ss1 = (float*)alloc((size_t)K0 * 4);
  float* score2 = (float*)alloc((size_t)K1 * 4);
  float* ss2 = (float*)alloc((size_t)K1 * 4);
  int* perm0 = (int*)alloc((size_t)K0 * 4);
  int* perm1 = (int*)alloc((size_t)K1 * 4);
  int* perm2 = (int*)alloc((size_t)K2 * 4);
  float* gate0 = (float*)alloc((size_t)K0 * 4);
  float* gate1 = (float*)alloc((size_t)K1 * 4);
  float* gate2 = (float*)alloc((size_t)K2 * 4);
  int* e1s = (int*)alloc((size_t)CAP1 * 4);
  int* e1d = (int*)alloc((size_t)CAP1 * 4);
  int* e2s = (int*)alloc((size_t)CAP2 * 4);
  int* e2d = (int*)alloc((size_t)CAP2 * 4);
  int* e3s = (int*)alloc((size_t)CAP3 * 4);
  int* e3d = (int*)alloc((size_t)CAP3 * 4);
  int* rowptr0 = (int*)alloc((size_t)(N0 + 1) * 4);
  int* rowptr1 = (int*)alloc((size_t)(K0 + 1) * 4);
  int* rowptr2 = (int*)alloc((size_t)(K1 + 1) * 4);
  int* rowptr3 = (int*)alloc((size_t)(K2 + 1) * 4);
  int* csr0 = (int*)alloc((size_t)E0 * 4);
  int* csr1 = (int*)alloc((size_t)CAP1 * 4);
  int* csr2 = (int*)alloc((size_t)CAP2 * 4);
  int* csr3 = (int*)alloc((size_t)CAP3 * 4);
  float* xp = (float*)alloc((size_t)K0 * C_ * 4);  // pooled input / hup2
  float* h0 = (float*)alloc((size_t)K0 * C_ * 4);  // down h0, later hup1
  float* h1 = (float*)alloc((size_t)K1 * C_ * 4);
  float* h2 = (float*)alloc((size_t)K2 * C_ * 4);
  float* mean = (float*)alloc((size_t)N0 * C_ * 4);

  uint* kth0 = (uint*)(ctrl + 8);
  uint* kth1 = (uint*)(ctrl + 9);
  uint* kth2 = (uint*)(ctrl + 10);
  float* Lacc = (float*)(ctrl + 16);
  const float sc0 = 1.f / ((float)K0 * C_);
  const float sc1 = 1.f / ((float)K1 * C_);
  const float sc2 = 1.f / ((float)K2 * C_);

  hipMemsetAsync(ctrl, 0, zero_bytes, stream);
  hipMemsetAsync(map0, 0xFF, ff_bytes, stream);

  // CSR over original edges (for the final conv)
  hist_kernel<<<2048, 256, 0, stream>>>(ei + E0, E0, cur0);
  scan_kernel<<<1, 1024, 0, stream>>>(cur0, rowptr0, N0);
  scatter_kernel<<<2048, 256, 0, stream>>>(ei, ei + E0, nullptr, E0, cur0, csr0);

  // ---------------- down level 0 ----------------
  score_kernel<<<N0 / 4, 256, 0, stream>>>(x0, score0, ss0);
  select_kernel<<<1, 1024, 0, stream>>>(score0, N0, K0, kth0, map0);
  build_perm_kernel<<<N0 / 256, 256, 0, stream>>>(score0, ss0, kth0, map0, perm0, gate0,
                                                  ctrl + 4, 0.f, Lacc);
  pool_gather_kernel<<<K0 / 8, 256, 0, stream>>>(x0, perm0, gate0, xp);
  edge_compact_kernel<<<2048, 256, 0, stream>>>(ei, ei + E0, nullptr, E0, map0, e1s, e1d,
                                                ctrl + 0, CAP1, cur1);
  scan_kernel<<<1, 1024, 0, stream>>>(cur1, rowptr1, K0);
  scatter_kernel<<<1024, 256, 0, stream>>>(e1s, e1d, ctrl + 0, CAP1, cur1, csr1);
  agg_kernel<<<K0 / 8, 256, 0, stream>>>(xp, rowptr1, csr1, nullptr, mean, K0);
  gemm_kernel<<<K0 / 64, 256, 0, stream>>>(mean, xp, nullptr, Wl, Wr, bias, h0, 1, nullptr, Lacc);
  lsim_score_kernel<<<K0 / 4, 256, 0, stream>>>(h0, x0, x0, perm0, sc0, Lacc, score1, ss1);

  // ---------------- down level 1 ----------------
  select_kernel<<<1, 1024, 0, stream>>>(score1, K0, K1, kth1, map1);
  build_perm_kernel<<<K0 / 256, 256, 0, stream>>>(score1, ss1, kth1, map1, perm1, gate1,
                                                  ctrl + 5, sc1, Lacc);  // + fused L_FP0
  pool_gather_kernel<<<K1 / 8, 256, 0, stream>>>(h0, perm1, gate1, xp);
  edge_compact_kernel<<<1024, 256, 0, stream>>>(e1s, e1d, ctrl + 0, CAP1, map1, e2s, e2d,
                                                ctrl + 1, CAP2, cur2);
  scan_kernel<<<1, 1024, 0, stream>>>(cur2, rowptr2, K1);
  scatter_kernel<<<512, 256, 0, stream>>>(e2s, e2d, ctrl + 1, CAP2, cur2, csr2);
  agg_kernel<<<K1 / 8, 256, 0, stream>>>(xp, rowptr2, csr2, nullptr, mean, K1);
  gemm_kernel<<<K1 / 64, 256, 0, stream>>>(mean, xp, nullptr, Wl + 16384, Wr + 16384, bias + 128,
                                           h1, 1, nullptr, Lacc);
  lsim_score_kernel<<<K1 / 4, 256, 0, stream>>>(h1, x0, h0, perm1, sc1, Lacc, score2, ss2);

  // ---------------- down level 2 ----------------
  select_kernel<<<1, 1024, 0, stream>>>(score2, K1, K2, kth2, map2);
  build_perm_kernel<<<K1 / 256, 256, 0, stream>>>(score2, ss2, kth2, map2, perm2, gate2,
                                                  ctrl + 6, sc2, Lacc);  // + fused L_FP1
  pool_gather_kernel<<<K2 / 8, 256, 0, stream>>>(h1, perm2, gate2, xp);
  edge_compact_kernel<<<512, 256, 0, stream>>>(e2s, e2d, ctrl + 1, CAP2, map2, e3s, e3d,
                                               ctrl + 2, CAP3, cur3);
  scan_kernel<<<1, 1024, 0, stream>>>(cur3, rowptr3, K2);
  scatter_kernel<<<256, 256, 0, stream>>>(e3s, e3d, ctrl + 2, CAP3, cur3, csr3);
  agg_kernel<<<K2 / 8, 256, 0, stream>>>(xp, rowptr3, csr3, nullptr, mean, K2);
  gemm_kernel<<<K2 / 64, 256, 0, stream>>>(mean, xp, nullptr, Wl + 2 * 16384, Wr + 2 * 16384,
                                           bias + 256, h2, 1, nullptr, Lacc);
  lsim_score_kernel<<<K2 / 4, 256, 0, stream>>>(h2, x0, h1, perm2, sc2, Lacc, nullptr, nullptr);

  // ---------------- up path: unpool is VIRTUAL (indirection via map) ----------
  // i = 2: conv idx 4 over level-2 graph (K1 nodes); x = h2 via map2; -> xp
  agg_kernel<<<K1 / 8, 256, 0, stream>>>(h2, rowptr2, csr2, map2, mean, K1);
  gemm_kernel<<<K1 / 64, 256, 0, stream>>>(mean, h2, map2, Wl + 4 * 16384, Wr + 4 * 16384,
                                           bias + 512, xp, 1, nullptr, Lacc);
  // i = 1: conv idx 3 over level-1 graph (K0 nodes); x = xp via map1; -> h0
  agg_kernel<<<K0 / 8, 256, 0, stream>>>(xp, rowptr1, csr1, map1, mean, K0);
  gemm_kernel<<<K0 / 64, 256, 0, stream>>>(mean, xp, map1, Wl + 3 * 16384, Wr + 3 * 16384,
                                           bias + 384, h0, 1, nullptr, Lacc);
  // final: conv idx 5 over original graph; x = h0 via map0; no relu; + L writeback
  agg_kernel<<<N0 / 8, 256, 0, stream>>>(h0, rowptr0, csr0, map0, mean, N0);
  gemm_kernel<<<N0 / 64, 256, 0, stream>>>(mean, h0, map0, Wl + 5 * 16384, Wr + 5 * 16384,
                                           bias + 640, out, 0, out + (size_t)N0 * C_, Lacc);
}

// Round 8
// 1410.285 us; speedup vs baseline: 1.1811x; 1.1474x over previous
//
#include <hip/hip_runtime.h>
#include <math.h>

typedef unsigned int uint;
typedef unsigned long long u64;

#define C_ 128
static const int N0 = 65536;
static const int E0 = 1048576;
static const int K0 = 32768, K1 = 16384, K2 = 8192;
static const int CAP1 = 524288, CAP2 = 262144, CAP3 = 131072;

__device__ inline float wave_reduce_sum(float v) {
#pragma unroll
  for (int w = 32; w >= 1; w >>= 1) v += __shfl_xor(v, w, 64);
  return v;
}

// per-row squared norm + score = sqrt(ss + 1e-12). One wave per row.
__global__ void score_kernel(const float* __restrict__ x, float* __restrict__ score,
                             float* __restrict__ ss) {
  int row = blockIdx.x * 4 + (threadIdx.x >> 6);
  int lane = threadIdx.x & 63;
  float2 v = ((const float2*)(x + (size_t)row * C_))[lane];
  float s = v.x * v.x + v.y * v.y;
  s = wave_reduce_sum(s);
  if (lane == 0) { ss[row] = s; score[row] = sqrtf(s + 1e-12f); }
}

// single-block radix select: kth largest key (float bits, all positive) +
// mark boundary-tie elements (lowest indices) with map[i] = -2.
__global__ __launch_bounds__(1024) void select_kernel(const float* __restrict__ score, int n,
                                                      int k, uint* __restrict__ kth_out,
                                                      int* __restrict__ map) {
  const uint* keys = (const uint*)score;
  const uint4* keys4 = (const uint4*)score;
  __shared__ int hist[256];
  __shared__ uint s_kth;
  __shared__ int s_rem;
  __shared__ int eqlist[2048];
  __shared__ int eqn;
  int tid = threadIdx.x;
  int lane = tid & 63;
  int n4 = n >> 2;
  if (tid == 0) { s_rem = k; s_kth = 0u; eqn = 0; }
  __syncthreads();
  for (int pass = 3; pass >= 0; --pass) {
    int sh = pass * 8;
    if (tid < 256) hist[tid] = 0;
    __syncthreads();
    uint prefix = s_kth;
    uint maskhi = (pass == 3) ? 0u : (0xFFFFFFFFu << (sh + 8));
    for (int i = tid; i < n4; i += 1024) {
      uint4 v4 = keys4[i];
#pragma unroll
      for (int c = 0; c < 4; ++c) {
        uint v = (c == 0) ? v4.x : (c == 1) ? v4.y : (c == 2) ? v4.z : v4.w;
        bool valid = (v & maskhi) == prefix;
        u64 m = __ballot(valid);
        if (!m) continue;  // wave-uniform: nobody matches prefix
        uint b = (v >> sh) & 255u;
#pragma unroll
        for (int bit = 0; bit < 8; ++bit) {
          u64 bb = __ballot((b >> bit) & 1u);
          m &= ((b >> bit) & 1u) ? bb : ~bb;
        }
        if (valid) {
          int leader = __ffsll(m) - 1;
          if (lane == leader) atomicAdd(&hist[b], (int)__popcll(m));
        }
      }
    }
    __syncthreads();
    if (tid == 0) {
      int rem = s_rem;
      int b = 255;
      for (;; --b) { int c = hist[b]; if (c >= rem) break; rem -= c; }
      s_rem = rem;
      s_kth = prefix | ((uint)b << sh);
    }
    __syncthreads();
  }
  uint kth = s_kth;
  for (int i = tid; i < n; i += 1024) {
    if (keys[i] == kth) { int p = atomicAdd(&eqn, 1); if (p < 2048) eqlist[p] = i; }
  }
  __syncthreads();
  if (tid == 0) {
    int need = s_rem;
    int tot = eqn < 2048 ? eqn : 2048;
    for (int t = 0; t < need && t < tot; ++t) {
      int mi = -1, mv = 0x7FFFFFFF;
      for (int q = 0; q < tot; ++q) { int v = eqlist[q]; if (v >= 0 && v < mv) { mv = v; mi = q; } }
      if (mi < 0) break;
      map[mv] = -2;
      eqlist[mi] = -1;
    }
    *kth_out = kth;
  }
}

// compact selected nodes -> perm/map/gate (+ optional fused L_FP term).
// ONE counter atomic per block (r6 post-mortem: per-wave atomics-with-return
// to a single address serialize at ~29 cyc each in the L2 -- the compiler
// already wave-aggregates per-lane atomics, so only block-level amortization
// helps). Two-pass: count -> block scan -> one atomicAdd -> ballot-slot write.
// Grid must satisfy grid*1024 == n.
__global__ __launch_bounds__(256) void build_perm_kernel(
    const float* __restrict__ score, const float* __restrict__ ss,
    const uint* __restrict__ kth_ptr, int* __restrict__ map, int* __restrict__ perm,
    float* __restrict__ gate, int* __restrict__ ctr, float lfp_scale,
    float* __restrict__ Lacc) {
  const int ITER = 4;
  int tid = threadIdx.x, lane = tid & 63, wid = tid >> 6;
  __shared__ int wbase[4];
  __shared__ int gbase;
  __shared__ float pl[4];
  uint kth = *kth_ptr;
  int base = blockIdx.x * (256 * ITER);
  // pass 1: count selected in this block's range
  int cnt = 0;
#pragma unroll
  for (int l = 0; l < ITER; ++l) {
    int i = base + l * 256 + tid;
    uint key = ((const uint*)score)[i];
    if ((key > kth) || (map[i] == -2)) ++cnt;
  }
#pragma unroll
  for (int w = 32; w >= 1; w >>= 1) cnt += __shfl_xor(cnt, w, 64);
  if (lane == 0) wbase[wid] = cnt;
  __syncthreads();
  if (tid == 0) {
    int s = 0;
#pragma unroll
    for (int i = 0; i < 4; ++i) { int c = wbase[i]; wbase[i] = s; s += c; }
    gbase = s ? atomicAdd(ctr, s) : 0;
  }
  __syncthreads();
  int woff = gbase + wbase[wid];
  // pass 2: write via ballot-prefix slots (map[i] only touched by its own thread)
  float lfp = 0.f;
#pragma unroll
  for (int l = 0; l < ITER; ++l) {
    int i = base + l * 256 + tid;
    uint key = ((const uint*)score)[i];
    bool sel = (key > kth) || (map[i] == -2);
    u64 m = __ballot(sel);
    if (sel) {
      int j = woff + (int)__popcll(m & ((1ull << lane) - 1ull));
      perm[j] = i;
      map[i] = j;
      float t = tanhf(score[i]);
      gate[j] = t;
      if (lfp_scale != 0.f) { float om = 1.f - t; lfp += om * om * ss[i] * lfp_scale; }
    }
    woff += (int)__popcll(m);
  }
  if (lfp_scale != 0.f) {
    lfp = wave_reduce_sum(lfp);
    if (lane == 0) pl[wid] = lfp;
    __syncthreads();
    if (tid == 0) atomicAdd(Lacc, pl[0] + pl[1] + pl[2] + pl[3]);
  }
}

// xp[j] = x[perm[j]] * gate[j]   (32 threads/row, float4)
__global__ void pool_gather_kernel(const float* __restrict__ xin, const int* __restrict__ perm,
                                   const float* __restrict__ gate, float* __restrict__ xp) {
  int t = blockIdx.x * 256 + threadIdx.x;
  int j = t >> 5, q = t & 31;
  int p = perm[j];
  float g = gate[j];
  float4 v = ((const float4*)(xin + (size_t)p * C_))[q];
  v.x *= g; v.y *= g; v.z *= g; v.w *= g;
  ((float4*)(xp + (size_t)j * C_))[q] = v;
}

// filter edges whose both endpoints survive; relabel; fused degree histogram.
// ONE output-counter atomic per 2048-edge block chunk (see build_perm note).
// Two-pass over the chunk: count -> block scan -> single atomicAdd -> write.
__global__ __launch_bounds__(256) void edge_compact_kernel(
    const int* __restrict__ src, const int* __restrict__ dst,
    const int* __restrict__ cnt_ptr, int in_cap, const int* __restrict__ map,
    int* __restrict__ osrc, int* __restrict__ odst, int* __restrict__ octr, int cap,
    int* __restrict__ deg) {
  const int ITER = 8;
  int n = cnt_ptr ? min(*cnt_ptr, in_cap) : in_cap;
  int tid = threadIdx.x, lane = tid & 63, wid = tid >> 6;
  __shared__ int wbase[4];
  __shared__ int gbase;
  long long chunk = 256 * ITER;
  for (long long base = (long long)blockIdx.x * chunk; base < n;
       base += (long long)gridDim.x * chunk) {
    // pass 1: count keeps in chunk (map is L2-hot; re-read in pass 2)
    int cnt = 0;
#pragma unroll
    for (int l = 0; l < ITER; ++l) {
      long long e = base + l * 256 + tid;
      if (e < n) {
        int a = map[src[e]];
        int b = map[dst[e]];
        if (a >= 0 && b >= 0) ++cnt;
      }
    }
#pragma unroll
    for (int w = 32; w >= 1; w >>= 1) cnt += __shfl_xor(cnt, w, 64);
    __syncthreads();  // protect LDS reuse across grid-stride iterations
    if (lane == 0) wbase[wid] = cnt;
    __syncthreads();
    if (tid == 0) {
      int s = 0;
#pragma unroll
      for (int i = 0; i < 4; ++i) { int c = wbase[i]; wbase[i] = s; s += c; }
      gbase = s ? atomicAdd(octr, s) : 0;
    }
    __syncthreads();
    int woff = gbase + wbase[wid];
    // pass 2: write via ballot-prefix slots
#pragma unroll
    for (int l = 0; l < ITER; ++l) {
      long long e = base + l * 256 + tid;
      int a = -1, b = -1;
      bool keep = false;
      if (e < n) {
        a = map[src[e]];
        b = map[dst[e]];
        keep = (a >= 0 && b >= 0);
      }
      u64 m = __ballot(keep);
      if (keep) {
        int p = woff + (int)__popcll(m & ((1ull << lane) - 1ull));
        if (p < cap) {
          osrc[p] = a;
          odst[p] = b;
          atomicAdd(&deg[b], 1);
        }
      }
      woff += (int)__popcll(m);
    }
  }
}

__global__ void hist_kernel(const int* __restrict__ dst, int n, int* __restrict__ deg) {
  for (int e = blockIdx.x * 256 + threadIdx.x; e < n; e += gridDim.x * 256)
    atomicAdd(&deg[dst[e]], 1);
}

// exclusive scan of degrees -> rowptr; cursor doubles as deg-in / offset-out.
__global__ __launch_bounds__(1024) void scan_kernel(int* __restrict__ cursor,
                                                    int* __restrict__ rowptr, int n) {
  __shared__ int part[1024];
  int tid = threadIdx.x;
  int chunk = (n + 1023) >> 10;
  int beg = tid * chunk, end = min(beg + chunk, n);
  int s = 0;
  for (int i = beg; i < end; ++i) s += cursor[i];
  part[tid] = s;
  __syncthreads();
  for (int d = 1; d < 1024; d <<= 1) {
    int v = part[tid];
    if (tid >= d) v += part[tid - d];
    __syncthreads();
    part[tid] = v;
    __syncthreads();
  }
  int off = part[tid] - s;
  for (int i = beg; i < end; ++i) { int dv = cursor[i]; rowptr[i] = off; cursor[i] = off; off += dv; }
  if (tid == 1023) rowptr[n] = part[1023];
}

__global__ void scatter_kernel(const int* __restrict__ src, const int* __restrict__ dst,
                               const int* __restrict__ cnt_ptr, int cap,
                               int* __restrict__ cursor, int* __restrict__ csr) {
  int n = cnt_ptr ? min(*cnt_ptr, cap) : cap;
  for (int e = blockIdx.x * 256 + threadIdx.x; e < n; e += gridDim.x * 256) {
    int p = atomicAdd(&cursor[dst[e]], 1);
    csr[p] = src[e];
  }
}

// mean[node] = (sum over CSR row) / max(deg,1). 32 threads/node, float4.
// fmap mode: source ids are in the PREVIOUS space; x row = x[fmap[s]] if
// selected, else contributes 0 (virtual unpool -- never materialized).
__global__ void agg_kernel(const float* __restrict__ x, const int* __restrict__ rowptr,
                           const int* __restrict__ csr, const int* __restrict__ fmap,
                           float* __restrict__ mean, int n) {
  int t = blockIdx.x * 256 + threadIdx.x;
  int node = t >> 5, q = t & 31;
  if (node >= n) return;
  int beg = rowptr[node], end = rowptr[node + 1];
  float4 acc = make_float4(0.f, 0.f, 0.f, 0.f);
  if (fmap) {
    for (int p = beg; p < end; ++p) {
      int m = fmap[csr[p]];
      if (m < 0) continue;
      float4 v = ((const float4*)(x + (size_t)m * C_))[q];
      acc.x += v.x; acc.y += v.y; acc.z += v.z; acc.w += v.w;
    }
  } else {
    for (int p = beg; p < end; ++p) {
      int s = csr[p];
      float4 v = ((const float4*)(x + (size_t)s * C_))[q];
      acc.x += v.x; acc.y += v.y; acc.z += v.z; acc.w += v.w;
    }
  }
  float inv = 1.f / fmaxf((float)(end - beg), 1.f);
  acc.x *= inv; acc.y *= inv; acc.z *= inv; acc.w *= inv;
  ((float4*)(mean + (size_t)node * C_))[q] = acc;
}

// out[row] = mean[row] @ Wl + Xsrc[xrow] @ Wr + b (optional relu).
// xmask==nullptr: Xsrc dense, xrow = row. xmask!=nullptr: xrow = xmask[row],
// rows with xmask<0 are zero (virtual unpool). Lout: fused loss writeback.
__global__ __launch_bounds__(256) void gemm_kernel(const float* __restrict__ Amean,
                                                   const float* __restrict__ Xsrc,
                                                   const int* __restrict__ xmask,
                                                   const float* __restrict__ Wl,
                                                   const float* __restrict__ Wr,
                                                   const float* __restrict__ bias,
                                                   float* __restrict__ out, int relu,
                                                   float* __restrict__ Lout,
                                                   const float* __restrict__ Lacc) {
  __shared__ alignas(16) float As[32][68];
  __shared__ alignas(16) float Ws[32][128];
  __shared__ int rm[64];
  int tid = threadIdx.x;
  int row0 = blockIdx.x * 64;
  if (tid < 64) rm[tid] = xmask ? xmask[row0 + tid] : (row0 + tid);
  if (Lout && blockIdx.x == 0 && tid == 0) Lout[0] = *Lacc;
  int trow = tid >> 4;  // 0..15 -> 4 rows each
  int tcol = tid & 15;  // 0..15 -> 8 cols each
  float acc[4][8];
#pragma unroll
  for (int i = 0; i < 4; ++i)
#pragma unroll
    for (int j = 0; j < 8; ++j) acc[i][j] = 0.f;
  __syncthreads();  // rm visible before phase-1 staging
  for (int phase = 0; phase < 2; ++phase) {
    const float* A = phase ? Xsrc : Amean;
    const float* W = phase ? Wr : Wl;
    for (int kc = 0; kc < 128; kc += 32) {
      // stage A chunk: 64 rows x 32 k, float4 granularity (512 float4, 2/thread)
#pragma unroll
      for (int l = 0; l < 2; ++l) {
        int f = tid + l * 256;
        int r = f >> 3, c4 = (f & 7) << 2;
        int xr = phase ? rm[r] : (row0 + r);
        float4 v = make_float4(0.f, 0.f, 0.f, 0.f);
        if (xr >= 0) v = *(const float4*)(A + (size_t)xr * C_ + kc + c4);
        As[c4 + 0][r] = v.x; As[c4 + 1][r] = v.y; As[c4 + 2][r] = v.z; As[c4 + 3][r] = v.w;
      }
      // stage W chunk: 32 k x 128 cols (1024 float4, 4/thread)
#pragma unroll
      for (int l = 0; l < 4; ++l) {
        int f = tid + l * 256;
        int kk = f >> 5, c4 = (f & 31) << 2;
        *(float4*)(&Ws[kk][c4]) = *(const float4*)(W + (size_t)(kc + kk) * C_ + c4);
      }
      __syncthreads();
#pragma unroll
      for (int kk = 0; kk < 32; ++kk) {
        float a[4], w[8];
#pragma unroll
        for (int i = 0; i < 4; ++i) a[i] = As[kk][trow * 4 + i];
#pragma unroll
        for (int j = 0; j < 8; ++j) w[j] = Ws[kk][tcol * 8 + j];
#pragma unroll
        for (int i = 0; i < 4; ++i)
#pragma unroll
          for (int j = 0; j < 8; ++j) acc[i][j] = fmaf(a[i], w[j], acc[i][j]);
      }
      __syncthreads();
    }
  }
#pragma unroll
  for (int i = 0; i < 4; ++i) {
    int r = row0 + trow * 4 + i;
#pragma unroll
    for (int j = 0; j < 8; ++j) {
      float v = acc[i][j] + bias[tcol * 8 + j];
      if (relu) v = fmaxf(v, 0.f);
      out[(size_t)r * C_ + tcol * 8 + j] = v;
    }
  }
}

// fused: L_similarity + L_regularization for one level, plus next level's
// score/ss (row norms of h). One wave per row.
__global__ void lsim_score_kernel(const float* __restrict__ h, const float* __restrict__ x0,
                                  const float* __restrict__ xin, const int* __restrict__ perm,
                                  float scale, float* __restrict__ Lacc,
                                  float* __restrict__ score, float* __restrict__ ss) {
  int row = blockIdx.x * 4 + (threadIdx.x >> 6);
  int lane = threadIdx.x & 63;
  int p = perm[row];
  float2 hv = ((const float2*)(h + (size_t)row * C_))[lane];
  float2 a = ((const float2*)(x0 + (size_t)p * C_))[lane];
  float2 bv = (xin == x0) ? a : ((const float2*)(xin + (size_t)p * C_))[lane];
  float d1x = hv.x - a.x, d1y = hv.y - a.y;
  float l = d1x * d1x + d1y * d1y + fabsf(hv.x - bv.x) + fabsf(hv.y - bv.y);
  float s2 = hv.x * hv.x + hv.y * hv.y;
#pragma unroll
  for (int w = 32; w >= 1; w >>= 1) { l += __shfl_xor(l, w, 64); s2 += __shfl_xor(s2, w, 64); }
  __shared__ float pl[4];
  int wid = threadIdx.x >> 6;
  if (lane == 0) {
    pl[wid] = l;
    if (score) { ss[row] = s2; score[row] = sqrtf(s2 + 1e-12f); }
  }
  __syncthreads();
  if (threadIdx.x == 0) atomicAdd(Lacc, (pl[0] + pl[1] + pl[2] + pl[3]) * scale);
}

extern "C" void kernel_launch(void* const* d_in, const int* in_sizes, int n_in, void* d_out,
                              int out_size, void* d_ws, size_t ws_size, hipStream_t stream) {
  const float* x0 = (const float*)d_in[0];
  const int* ei = (const int*)d_in[1];
  const float* Wl = (const float*)d_in[2];
  const float* Wr = (const float*)d_in[3];
  const float* bias = (const float*)d_in[4];
  float* out = (float*)d_out;

  char* base = (char*)d_ws;
  size_t off = 0;
  auto alloc = [&](size_t bytes) -> char* {
    char* p = base + off;
    off = (off + bytes + 255) & ~(size_t)255;
    return p;
  };

  // ---- zeroed region (one memset) ----
  int* ctrl = (int*)alloc(1024 * 4);
  // ctrl ints: 0..2 edge counters, 4..6 perm counters, 8..10 kth keys, 16 Lacc(float)
  int* cur0 = (int*)alloc((size_t)(N0 + 1) * 4);
  int* cur1 = (int*)alloc((size_t)(K0 + 1) * 4);
  int* cur2 = (int*)alloc((size_t)(K1 + 1) * 4);
  int* cur3 = (int*)alloc((size_t)(K2 + 1) * 4);
  size_t zero_bytes = (size_t)((base + off) - (char*)ctrl);
  // ---- 0xFF region (one memset) ----
  int* map0 = (int*)alloc((size_t)N0 * 4);
  int* map1 = (int*)alloc((size_t)K0 * 4);
  int* map2 = (int*)alloc((size_t)K1 * 4);
  size_t ff_bytes = (size_t)((base + off) - (char*)map0);
  // ---- uninitialized (fully written before read every call) ----
  float* score0 = (float*)alloc((size_t)N0 * 4);
  float* ss0 = (float*)alloc((size_t)N0 * 4);
  float* score1 = (float*)alloc((size_t)K0 * 4);
  float* ss1 = (float*)alloc((size_t)K0 * 4);
  float* score2 = (float*)alloc((size_t)K1 * 4);
  float* ss2 = (float*)alloc((size_t)K1 * 4);
  int* perm0 = (int*)alloc((size_t)K0 * 4);
  int* perm1 = (int*)alloc((size_t)K1 * 4);
  int* perm2 = (int*)alloc((size_t)K2 * 4);
  float* gate0 = (float*)alloc((size_t)K0 * 4);
  float* gate1 = (float*)alloc((size_t)K1 * 4);
  float* gate2 = (float*)alloc((size_t)K2 * 4);
  int* e1s = (int*)alloc((size_t)CAP1 * 4);
  int* e1d = (int*)alloc((size_t)CAP1 * 4);
  int* e2s = (int*)alloc((size_t)CAP2 * 4);
  int* e2d = (int*)alloc((size_t)CAP2 * 4);
  int* e3s = (int*)alloc((size_t)CAP3 * 4);
  int* e3d = (int*)alloc((size_t)CAP3 * 4);
  int* rowptr0 = (int*)alloc((size_t)(N0 + 1) * 4);
  int* rowptr1 = (int*)alloc((size_t)(K0 + 1) * 4);
  int* rowptr2 = (int*)alloc((size_t)(K1 + 1) * 4);
  int* rowptr3 = (int*)alloc((size_t)(K2 + 1) * 4);
  int* csr0 = (int*)alloc((size_t)E0 * 4);
  int* csr1 = (int*)alloc((size_t)CAP1 * 4);
  int* csr2 = (int*)alloc((size_t)CAP2 * 4);
  int* csr3 = (int*)alloc((size_t)CAP3 * 4);
  float* xp = (float*)alloc((size_t)K0 * C_ * 4);  // pooled input / hup2
  float* h0 = (float*)alloc((size_t)K0 * C_ * 4);  // down h0, later hup1
  float* h1 = (float*)alloc((size_t)K1 * C_ * 4);
  float* h2 = (float*)alloc((size_t)K2 * C_ * 4);
  float* mean = (float*)alloc((size_t)N0 * C_ * 4);

  uint* kth0 = (uint*)(ctrl + 8);
  uint* kth1 = (uint*)(ctrl + 9);
  uint* kth2 = (uint*)(ctrl + 10);
  float* Lacc = (float*)(ctrl + 16);
  const float sc0 = 1.f / ((float)K0 * C_);
  const float sc1 = 1.f / ((float)K1 * C_);
  const float sc2 = 1.f / ((float)K2 * C_);

  hipMemsetAsync(ctrl, 0, zero_bytes, stream);
  hipMemsetAsync(map0, 0xFF, ff_bytes, stream);

  // CSR over original edges (for the final conv)
  hist_kernel<<<2048, 256, 0, stream>>>(ei + E0, E0, cur0);
  scan_kernel<<<1, 1024, 0, stream>>>(cur0, rowptr0, N0);
  scatter_kernel<<<2048, 256, 0, stream>>>(ei, ei + E0, nullptr, E0, cur0, csr0);

  // ---------------- down level 0 ----------------
  score_kernel<<<N0 / 4, 256, 0, stream>>>(x0, score0, ss0);
  select_kernel<<<1, 1024, 0, stream>>>(score0, N0, K0, kth0, map0);
  build_perm_kernel<<<N0 / 1024, 256, 0, stream>>>(score0, ss0, kth0, map0, perm0, gate0,
                                                   ctrl + 4, 0.f, Lacc);
  pool_gather_kernel<<<K0 / 8, 256, 0, stream>>>(x0, perm0, gate0, xp);
  edge_compact_kernel<<<512, 256, 0, stream>>>(ei, ei + E0, nullptr, E0, map0, e1s, e1d,
                                               ctrl + 0, CAP1, cur1);
  scan_kernel<<<1, 1024, 0, stream>>>(cur1, rowptr1, K0);
  scatter_kernel<<<1024, 256, 0, stream>>>(e1s, e1d, ctrl + 0, CAP1, cur1, csr1);
  agg_kernel<<<K0 / 8, 256, 0, stream>>>(xp, rowptr1, csr1, nullptr, mean, K0);
  gemm_kernel<<<K0 / 64, 256, 0, stream>>>(mean, xp, nullptr, Wl, Wr, bias, h0, 1, nullptr, Lacc);
  lsim_score_kernel<<<K0 / 4, 256, 0, stream>>>(h0, x0, x0, perm0, sc0, Lacc, score1, ss1);

  // ---------------- down level 1 ----------------
  select_kernel<<<1, 1024, 0, stream>>>(score1, K0, K1, kth1, map1);
  build_perm_kernel<<<K0 / 1024, 256, 0, stream>>>(score1, ss1, kth1, map1, perm1, gate1,
                                                   ctrl + 5, sc1, Lacc);  // + fused L_FP0
  pool_gather_kernel<<<K1 / 8, 256, 0, stream>>>(h0, perm1, gate1, xp);
  edge_compact_kernel<<<256, 256, 0, stream>>>(e1s, e1d, ctrl + 0, CAP1, map1, e2s, e2d,
                                               ctrl + 1, CAP2, cur2);
  scan_kernel<<<1, 1024, 0, stream>>>(cur2, rowptr2, K1);
  scatter_kernel<<<512, 256, 0, stream>>>(e2s, e2d, ctrl + 1, CAP2, cur2, csr2);
  agg_kernel<<<K1 / 8, 256, 0, stream>>>(xp, rowptr2, csr2, nullptr, mean, K1);
  gemm_kernel<<<K1 / 64, 256, 0, stream>>>(mean, xp, nullptr, Wl + 16384, Wr + 16384, bias + 128,
                                           h1, 1, nullptr, Lacc);
  lsim_score_kernel<<<K1 / 4, 256, 0, stream>>>(h1, x0, h0, perm1, sc1, Lacc, score2, ss2);

  // ---------------- down level 2 ----------------
  select_kernel<<<1, 1024, 0, stream>>>(score2, K1, K2, kth2, map2);
  build_perm_kernel<<<K1 / 1024, 256, 0, stream>>>(score2, ss2, kth2, map2, perm2, gate2,
                                                   ctrl + 6, sc2, Lacc);  // + fused L_FP1
  pool_gather_kernel<<<K2 / 8, 256, 0, stream>>>(h1, perm2, gate2, xp);
  edge_compact_kernel<<<128, 256, 0, stream>>>(e2s, e2d, ctrl + 1, CAP2, map2, e3s, e3d,
                                               ctrl + 2, CAP3, cur3);
  scan_kernel<<<1, 1024, 0, stream>>>(cur3, rowptr3, K2);
  scatter_kernel<<<256, 256, 0, stream>>>(e3s, e3d, ctrl + 2, CAP3, cur3, csr3);
  agg_kernel<<<K2 / 8, 256, 0, stream>>>(xp, rowptr3, csr3, nullptr, mean, K2);
  gemm_kernel<<<K2 / 64, 256, 0, stream>>>(mean, xp, nullptr, Wl + 2 * 16384, Wr + 2 * 16384,
                                           bias + 256, h2, 1, nullptr, Lacc);
  lsim_score_kernel<<<K2 / 4, 256, 0, stream>>>(h2, x0, h1, perm2, sc2, Lacc, nullptr, nullptr);

  // ---------------- up path: unpool is VIRTUAL (indirection via map) ----------
  // i = 2: conv idx 4 over level-2 graph (K1 nodes); x = h2 via map2; -> xp
  agg_kernel<<<K1 / 8, 256, 0, stream>>>(h2, rowptr2, csr2, map2, mean, K1);
  gemm_kernel<<<K1 / 64, 256, 0, stream>>>(mean, h2, map2, Wl + 4 * 16384, Wr + 4 * 16384,
                                           bias + 512, xp, 1, nullptr, Lacc);
  // i = 1: conv idx 3 over level-1 graph (K0 nodes); x = xp via map1; -> h0
  agg_kernel<<<K0 / 8, 256, 0, stream>>>(xp, rowptr1, csr1, map1, mean, K0);
  gemm_kernel<<<K0 / 64, 256, 0, stream>>>(mean, xp, map1, Wl + 3 * 16384, Wr + 3 * 16384,
                                           bias + 384, h0, 1, nullptr, Lacc);
  // final: conv idx 5 over original graph; x = h0 via map0; no relu; + L writeback
  agg_kernel<<<N0 / 8, 256, 0, stream>>>(h0, rowptr0, csr0, map0, mean, N0);
  gemm_kernel<<<N0 / 64, 256, 0, stream>>>(mean, h0, map0, Wl + 5 * 16384, Wr + 5 * 16384,
                                           bias + 640, out, 0, out + (size_t)N0 * C_, Lacc);
}